// Round 2
// baseline (577.770 us; speedup 1.0000x reference)
//
#include <hip/hip_runtime.h>
#include <stdint.h>

// LossRecovery via Gram-matrix collapse.
//   G1 = X^T X, GS = sum_s x_s x_swap(s)^T (symmetric).
//   logits1 = Wq G1 Wk^T + rank1;  x1 = X W1^T + b1 (W1 = I + gs*attn1*Wv, never materialize x1)
//   logits2 = Wtq (W1 GS + b1 u^T) Wtk^T + rank1
//   out = gather(v2)·(gt*attn2) + X W1^T + b1   (single fused final GEMM)
// Split-bf16 (hi/lo, 3-pass MFMA) on all logit-path GEMMs; plain bf16 on v2/PV.

#define S4 4096
#define CH 256

typedef __attribute__((ext_vector_type(8))) short bf16x8;
typedef __attribute__((ext_vector_type(4))) float f32x4;

static __device__ __forceinline__ float bf2f(unsigned short u){
  union { unsigned int i; float f; } v; v.i = ((unsigned int)u) << 16; return v.f;
}
static __device__ __forceinline__ unsigned short f2bf(float f){
  union { float f; unsigned int i; } v; v.f = f;
  unsigned int x = v.i;
  x += 0x7fffu + ((x >> 16) & 1u);   // RNE
  return (unsigned short)(x >> 16);
}
static __device__ __forceinline__ void gload16(const void* g, void* l){
  __builtin_amdgcn_global_load_lds((const __attribute__((address_space(1))) void*)g,
                                   (__attribute__((address_space(3))) void*)l, 16, 0, 0);
}

// ---------------- prep ----------------

__global__ void k_xprep(const float* __restrict__ x,
                        unsigned short* __restrict__ xhi,
                        unsigned short* __restrict__ xlo){
  int row = blockIdx.x;           // bl*4096 + s
  int c   = threadIdx.x;          // 0..255
  float v = x[(size_t)row*259 + c];
  unsigned short h = f2bf(v);
  xhi[(size_t)row*256 + c] = h;
  xlo[(size_t)row*256 + c] = f2bf(v - bf2f(h));
}

__global__ void k_wprep(const float* __restrict__ w0, const float* __restrict__ w1,
                        const float* __restrict__ w2, const float* __restrict__ w3,
                        const float* __restrict__ w4, const float* __restrict__ w5,
                        unsigned short* __restrict__ whi, unsigned short* __restrict__ wlo,
                        unsigned short* __restrict__ wvthi, unsigned short* __restrict__ wvtlo){
  int i = blockIdx.x*256 + threadIdx.x;   // 0 .. 7*65536
  int mat = i >> 16; int off = i & 65535;
  if (mat < 6){
    const float* src = mat==0?w0:mat==1?w1:mat==2?w2:mat==3?w3:mat==4?w4:w5;
    float v = src[off];
    unsigned short h = f2bf(v);
    whi[i] = h;
    wlo[i] = f2bf(v - bf2f(h));
  } else {
    int e = off >> 8, d = off & 255;
    float v = w2[d*256 + e];              // WvT[e][d] = sv_w[d][e]
    unsigned short h = f2bf(v);
    wvthi[off] = h;
    wvtlo[off] = f2bf(v - bf2f(h));
  }
}

// ---------------- tiny vector kernels ----------------

__global__ void k_colsum(const float* __restrict__ x, float* __restrict__ ups){
  int bl = blockIdx.x, ch = blockIdx.y, e = threadIdx.x;
  float s = 0.f;
  for (int i=0;i<128;++i){
    int row = bl*4096 + ch*128 + i;
    s += x[(size_t)row*259 + e];
  }
  ups[(bl*32 + ch)*256 + e] = s;
}

__global__ void k_vecfin(const float* __restrict__ ups, float* __restrict__ u){
  int bl = blockIdx.x, e = threadIdx.x;
  float s = 0.f;
  for (int ch=0;ch<32;++ch) s += ups[(bl*32+ch)*256 + e];
  u[bl*256 + e] = s;
}

// wq_u'[c] = Wq u + 4096*bq ; wk_u = Wk u ; wtk_u = Wtk u
__global__ void k_vecs1(const float* __restrict__ sq_w, const float* __restrict__ sq_b,
                        const float* __restrict__ sk_w, const float* __restrict__ tk_w,
                        const float* __restrict__ u,
                        float* __restrict__ wqu, float* __restrict__ wku, float* __restrict__ wtku){
  int bl = blockIdx.x, mat = blockIdx.y;
  const float* W = mat==0? sq_w : mat==1? sk_w : tk_w;
  int l = threadIdx.x & 63, w = threadIdx.x >> 6;
  const float* ub = u + bl*256;
  for (int i=0;i<64;++i){
    int c = w*64 + i;
    float s = 0.f;
    #pragma unroll
    for (int j=0;j<4;++j) s += W[c*256 + l + 64*j] * ub[l + 64*j];
    #pragma unroll
    for (int off=32; off; off>>=1) s += __shfl_xor(s, off, 64);
    if (l==0){
      if (mat==0) wqu [bl*256+c] = s + 4096.f*sq_b[c];
      else if (mat==1) wku [bl*256+c] = s;
      else wtku[bl*256+c] = s;
    }
  }
}

// c1 = attn1*bv ; m1u = M1*u
__global__ void k_vecs2a(const unsigned short* __restrict__ a1hi, const unsigned short* __restrict__ a1lo,
                         const float* __restrict__ bv, const float* __restrict__ M1,
                         const float* __restrict__ u,
                         float* __restrict__ c1, float* __restrict__ m1u){
  int bl = blockIdx.x, mat = blockIdx.y;
  int l = threadIdx.x & 63, w = threadIdx.x >> 6;
  for (int i=0;i<64;++i){
    int c = w*64 + i;
    float s = 0.f;
    if (mat==0){
      #pragma unroll
      for (int j=0;j<4;++j){
        long o = (long)bl*65536 + c*256 + l + 64*j;
        s += (bf2f(a1hi[o]) + bf2f(a1lo[o])) * bv[l + 64*j];
      }
    } else {
      #pragma unroll
      for (int j=0;j<4;++j)
        s += M1[(long)bl*65536 + c*256 + l + 64*j] * u[bl*256 + l + 64*j];
    }
    #pragma unroll
    for (int off=32; off; off>>=1) s += __shfl_xor(s, off, 64);
    if (l==0){
      if (mat==0) c1 [bl*256+c] = s;
      else        m1u[bl*256+c] = s;
    }
  }
}

// b1eff = gs*c1 ; h1 = u + gs*m1u + 4096*b1eff ; wtqh'[c] = Wtq h1 + 4096*btq
__global__ void k_vecs2b(const float* __restrict__ u, const float* __restrict__ m1u,
                         const float* __restrict__ c1, const float* __restrict__ s_g,
                         const float* __restrict__ tq_w, const float* __restrict__ tq_b,
                         float* __restrict__ b1eff, float* __restrict__ wtqh){
  __shared__ float h1[256];
  int bl = blockIdx.x, tid = threadIdx.x;
  float g = s_g[0];
  float b1 = g * c1[bl*256 + tid];
  b1eff[bl*256 + tid] = b1;
  h1[tid] = u[bl*256+tid] + g*m1u[bl*256+tid] + 4096.f*b1;
  __syncthreads();
  int l = tid & 63, w = tid >> 6;
  for (int i=0;i<64;++i){
    int c = w*64 + i;
    float s = 0.f;
    #pragma unroll
    for (int j=0;j<4;++j) s += tq_w[c*256 + l + 64*j] * h1[l + 64*j];
    #pragma unroll
    for (int off=32; off; off>>=1) s += __shfl_xor(s, off, 64);
    if (l==0) wtqh[bl*256+c] = s + 4096.f*tq_b[c];
  }
}

// W1 = I + gs*M1 -> hi/lo
__global__ void k_w1eff(const float* __restrict__ M1, const float* __restrict__ s_g,
                        unsigned short* __restrict__ w1hi, unsigned short* __restrict__ w1lo){
  int bl = blockIdx.y;
  int idx = blockIdx.x*256 + threadIdx.x;   // 0..65535
  int c = idx >> 8, e = idx & 255;
  float v = ((c==e)?1.f:0.f) + s_g[0]*M1[(long)bl*65536 + idx];
  unsigned short h = f2bf(v);
  w1hi[(long)bl*65536 + idx] = h;
  w1lo[(long)bl*65536 + idx] = f2bf(v - bf2f(h));
}

// combine 4 Gram partials -> hi/lo
__global__ void k_gcomb(const float* __restrict__ Gp,
                        unsigned short* __restrict__ ghi, unsigned short* __restrict__ glo){
  int bl = blockIdx.y;
  int idx = blockIdx.x*256 + threadIdx.x;
  float s = 0.f;
  #pragma unroll
  for (int p=0;p<4;++p) s += Gp[(long)(bl*4+p)*65536 + idx];
  unsigned short h = f2bf(s);
  ghi[(long)bl*65536 + idx] = h;
  glo[(long)bl*65536 + idx] = f2bf(s - bf2f(h));
}

// softmax over d. MODE 0: write hi+lo. MODE 1: write gt*p (hi only).
template<int MODE>
__global__ void k_softmax(const float* __restrict__ lp, const float* __restrict__ gp,
                          unsigned short* __restrict__ ahi, unsigned short* __restrict__ alo){
  int tid = threadIdx.x;
  int l = tid & 63, w = tid >> 6;
  int row = blockIdx.x*4 + w;         // 0..4095
  int bl = row >> 8, c = row & 255;
  const float* b0 = lp + (long)bl*65536 + c*256 + l*4;
  float4 v = *(const float4*)b0;
  float m = fmaxf(fmaxf(v.x,v.y), fmaxf(v.z,v.w));
  #pragma unroll
  for (int off=32; off; off>>=1) m = fmaxf(m, __shfl_xor(m, off, 64));
  float e0=__expf(v.x-m), e1=__expf(v.y-m), e2=__expf(v.z-m), e3=__expf(v.w-m);
  float s = e0+e1+e2+e3;
  #pragma unroll
  for (int off=32; off; off>>=1) s += __shfl_xor(s, off, 64);
  float inv = 1.f/s;
  if (MODE==1) inv *= gp[0];
  float p[4] = {e0*inv, e1*inv, e2*inv, e3*inv};
  long o = (long)bl*65536 + c*256 + l*4;
  ushort4 hh;
  hh.x=f2bf(p[0]); hh.y=f2bf(p[1]); hh.z=f2bf(p[2]); hh.w=f2bf(p[3]);
  *(ushort4*)(ahi + o) = hh;
  if (MODE==0){
    ushort4 ll;
    ll.x=f2bf(p[0]-bf2f(hh.x)); ll.y=f2bf(p[1]-bf2f(hh.y));
    ll.z=f2bf(p[2]-bf2f(hh.z)); ll.w=f2bf(p[3]-bf2f(hh.w));
    *(ushort4*)(alo + o) = ll;
  }
}

// ---------------- generic K=256 GEMM ----------------
// C[m][n] = sum_k (Ahi+Alo)[m][k]*(Bhi+Blo)[n][k], k-contiguous, z = bl (16).
// OUT_MODE: 0 bf16 hi/lo (+opt rank1), 1 bf16 single + per-m bias, 2 fp32 raw, 5 fp32 + rank1.

template<bool SPLIT,int OUT_MODE>
__global__ __launch_bounds__(256) void k_gemm(
  const unsigned short* __restrict__ Ahi, const unsigned short* __restrict__ Alo,
  long Abl, int Ars,
  const unsigned short* __restrict__ Bhi, const unsigned short* __restrict__ Blo,
  long Bbl, int Brs,
  const float* __restrict__ bias,
  const float* __restrict__ r1a, int r1as, const float* __restrict__ r1b, int r1bs,
  const float* __restrict__ r2a, int r2as, const float* __restrict__ r2b, int r2bs,
  unsigned short* __restrict__ O16a, unsigned short* __restrict__ O16b,
  float* __restrict__ O32, long Obl, int Ors)
{
  constexpr int LDSZ = SPLIT ? 65536 : 32768;
  __shared__ char lds[LDSZ];
  char* ldsAh = lds;
  char* ldsAl = lds + 16384;
  char* ldsBh = lds + (SPLIT ? 32768 : 16384);
  char* ldsBl = lds + 49152;

  const int tid = threadIdx.x;
  const int l   = tid & 63;
  const int wid = tid >> 6;
  const int wm  = wid >> 1, wn = wid & 1;
  const int lm  = l & 15, lk = l >> 4;
  const int fm  = wm*64, fn = wn*64;
  const int bl  = blockIdx.z;
  const int m0  = blockIdx.x * 128;
  const int n0  = blockIdx.y * 128;

  f32x4 acc[4][4];
  #pragma unroll
  for (int i=0;i<4;++i)
    #pragma unroll
    for (int j=0;j<4;++j) acc[i][j] = (f32x4){0.f,0.f,0.f,0.f};

  for (int kt = 0; kt < 4; ++kt) {
    const int kq = kt << 6;
    #pragma unroll
    for (int it=0; it<4; ++it) {
      int idx = it*256 + tid;
      int r = idx >> 3;
      int kb = ((idx & 7) << 4) ^ ((r & 7) << 4);
      long ga = (long)bl*Abl + (long)(m0 + r)*Ars + kq + (kb >> 1);
      gload16(Ahi + ga, ldsAh + idx*16);
      if (SPLIT) gload16(Alo + ga, ldsAl + idx*16);
      long gb = (long)bl*Bbl + (long)(n0 + r)*Brs + kq + (kb >> 1);
      gload16(Bhi + gb, ldsBh + idx*16);
      if (SPLIT) gload16(Blo + gb, ldsBl + idx*16);
    }
    __syncthreads();
    #pragma unroll
    for (int kk=0; kk<2; ++kk) {
      bf16x8 ah[4], al_[4];
      #pragma unroll
      for (int i=0;i<4;++i) {
        int r = fm + i*16 + lm;
        int kb = ((kk<<6) + (lk<<4)) ^ ((r & 7) << 4);
        ah[i] = *(const bf16x8*)(ldsAh + r*128 + kb);
        if (SPLIT) al_[i] = *(const bf16x8*)(ldsAl + r*128 + kb);
      }
      #pragma unroll
      for (int j=0;j<4;++j) {
        int r = fn + j*16 + lm;
        int kb = ((kk<<6) + (lk<<4)) ^ ((r & 7) << 4);
        bf16x8 bh = *(const bf16x8*)(ldsBh + r*128 + kb);
        bf16x8 bl8;
        if (SPLIT) bl8 = *(const bf16x8*)(ldsBl + r*128 + kb);
        #pragma unroll
        for (int i=0;i<4;++i) {
          acc[i][j] = __builtin_amdgcn_mfma_f32_16x16x32_bf16(ah[i], bh, acc[i][j], 0, 0, 0);
          if (SPLIT) {
            acc[i][j] = __builtin_amdgcn_mfma_f32_16x16x32_bf16(ah[i], bl8, acc[i][j], 0, 0, 0);
            acc[i][j] = __builtin_amdgcn_mfma_f32_16x16x32_bf16(al_[i], bh, acc[i][j], 0, 0, 0);
          }
        }
      }
    }
    __syncthreads();
  }

  // epilogue via LDS re-tile
  float* ldsF = (float*)lds;
  #pragma unroll
  for (int chv=0; chv<4; ++chv) {
    __syncthreads();
    if (wm == (chv >> 1)) {
      #pragma unroll
      for (int i2=0;i2<2;++i2) {
        int i = (chv & 1)*2 + i2;
        #pragma unroll
        for (int j=0;j<4;++j) {
          int n = fn + j*16 + lm;
          int m2 = i2*16 + lk*4;
          #pragma unroll
          for (int r2=0;r2<4;++r2) ldsF[(m2+r2)*136 + n] = acc[i][j][r2];
        }
      }
    }
    __syncthreads();
    #pragma unroll
    for (int g2=0; g2<2; ++g2) {
      int t2 = g2*256 + tid;
      int rr = t2 >> 4;
      int co = (t2 & 15) * 8;
      float v[8];
      #pragma unroll
      for (int e=0;e<8;++e) v[e] = ldsF[rr*136 + co + e];
      int mg = m0 + chv*32 + rr;
      int ng = n0 + co;
      long oidx = (long)bl*Obl + (long)mg*Ors + ng;
      if (OUT_MODE==0 || OUT_MODE==5){
        if (r1a){
          float a1 = r1a[bl*r1as + mg];
          #pragma unroll
          for (int e=0;e<8;++e) v[e] += a1 * r1b[bl*r1bs + ng + e];
        }
        if (r2a){
          float a2 = r2a[bl*r2as + mg];
          #pragma unroll
          for (int e=0;e<8;++e) v[e] += a2 * r2b[bl*r2bs + ng + e];
        }
      }
      if (OUT_MODE==2 || OUT_MODE==5){
        float4 o0, o1;
        o0.x=v[0]; o0.y=v[1]; o0.z=v[2]; o0.w=v[3];
        o1.x=v[4]; o1.y=v[5]; o1.z=v[6]; o1.w=v[7];
        *(float4*)(O32 + oidx)     = o0;
        *(float4*)(O32 + oidx + 4) = o1;
      } else {
        if (OUT_MODE==1){
          float b = bias ? bias[mg] : 0.f;
          #pragma unroll
          for (int e=0;e<8;++e) v[e] += b;
        }
        union { int4 vv; unsigned short u[8]; } hh, ll;
        #pragma unroll
        for (int e=0;e<8;++e) hh.u[e] = f2bf(v[e]);
        *(int4*)(O16a + oidx) = hh.vv;
        if (OUT_MODE==0){
          #pragma unroll
          for (int e=0;e<8;++e) ll.u[e] = f2bf(v[e] - bf2f(hh.u[e]));
          *(int4*)(O16b + oidx) = ll.vv;
        }
      }
    }
  }
}

// ---------------- Gram kernel (NT: C[e][f] = sum_s X[s][e] * Xsw[s][f]) ----------------
// split 3-pass; partials to Gp[z], z = bl*4 + sp.

template<bool BSWAP>
__global__ __launch_bounds__(256) void k_gram(
  const unsigned short* __restrict__ Xhi, const unsigned short* __restrict__ Xlo,
  float* __restrict__ Gp)
{
  __shared__ char lds[65536];
  char* ldsAh = lds;
  char* ldsAl = lds + 16384;
  char* ldsBh = lds + 32768;
  char* ldsBl = lds + 49152;

  const int tid = threadIdx.x;
  const int l = tid & 63, wid = tid >> 6;
  const int wm = wid >> 1, wn = wid & 1;
  const int lm = l & 15, lk = l >> 4;
  const int fm = wm*64, fn = wn*64;
  const int z = blockIdx.z, bl = z >> 2, sp = z & 3;
  const int m0 = blockIdx.x*128, n0 = blockIdx.y*128;
  const long Xoff = (long)bl * (4096*256);

  f32x4 acc[4][4];
  #pragma unroll
  for (int i=0;i<4;++i)
    #pragma unroll
    for (int j=0;j<4;++j) acc[i][j] = (f32x4){0.f,0.f,0.f,0.f};

  for (int kt=0; kt<16; ++kt) {
    const int k0 = sp*1024 + kt*64;
    #pragma unroll
    for (int it=0; it<4; ++it) {
      int idx = it*256 + tid;
      int s = idx & 63, ch = idx >> 6;
      int sa = k0 + s;
      int sb = BSWAP ? (((sa & 63) << 6) | (sa >> 6)) : sa;
      long gaA = Xoff + (long)sa*256 + m0 + ch*8;
      long gaB = Xoff + (long)sb*256 + n0 + ch*8;
      union { int4 v; unsigned short u[8]; } vh, vl, wh, wl;
      vh.v = *(const int4*)(Xhi + gaA);
      vl.v = *(const int4*)(Xlo + gaA);
      wh.v = *(const int4*)(Xhi + gaB);
      wl.v = *(const int4*)(Xlo + gaB);
      #pragma unroll
      for (int j=0;j<8;++j) {
        int e = ch*8 + j;
        int bo = e*128 + ((s*2) ^ ((e&7)<<4));
        *(unsigned short*)(ldsAh + bo) = vh.u[j];
        *(unsigned short*)(ldsAl + bo) = vl.u[j];
        *(unsigned short*)(ldsBh + bo) = wh.u[j];
        *(unsigned short*)(ldsBl + bo) = wl.u[j];
      }
    }
    __syncthreads();
    #pragma unroll
    for (int kk=0; kk<2; ++kk) {
      bf16x8 ah[4], al_[4];
      #pragma unroll
      for (int i=0;i<4;++i) {
        int r = fm + i*16 + lm;
        int kb = ((kk<<6) + (lk<<4)) ^ ((r & 7) << 4);
        ah[i]  = *(const bf16x8*)(ldsAh + r*128 + kb);
        al_[i] = *(const bf16x8*)(ldsAl + r*128 + kb);
      }
      #pragma unroll
      for (int j=0;j<4;++j) {
        int r = fn + j*16 + lm;
        int kb = ((kk<<6) + (lk<<4)) ^ ((r & 7) << 4);
        bf16x8 bh  = *(const bf16x8*)(ldsBh + r*128 + kb);
        bf16x8 bl8 = *(const bf16x8*)(ldsBl + r*128 + kb);
        #pragma unroll
        for (int i=0;i<4;++i) {
          acc[i][j] = __builtin_amdgcn_mfma_f32_16x16x32_bf16(ah[i], bh, acc[i][j], 0, 0, 0);
          acc[i][j] = __builtin_amdgcn_mfma_f32_16x16x32_bf16(ah[i], bl8, acc[i][j], 0, 0, 0);
          acc[i][j] = __builtin_amdgcn_mfma_f32_16x16x32_bf16(al_[i], bh, acc[i][j], 0, 0, 0);
        }
      }
    }
    __syncthreads();
  }

  float* ldsF = (float*)lds;
  #pragma unroll
  for (int chv=0; chv<4; ++chv) {
    __syncthreads();
    if (wm == (chv >> 1)) {
      #pragma unroll
      for (int i2=0;i2<2;++i2) {
        int i = (chv & 1)*2 + i2;
        #pragma unroll
        for (int j=0;j<4;++j) {
          int n = fn + j*16 + lm;
          int m2 = i2*16 + lk*4;
          #pragma unroll
          for (int r2=0;r2<4;++r2) ldsF[(m2+r2)*136 + n] = acc[i][j][r2];
        }
      }
    }
    __syncthreads();
    #pragma unroll
    for (int g2=0; g2<2; ++g2) {
      int t2 = g2*256 + tid;
      int rr = t2 >> 4;
      int co = (t2 & 15) * 8;
      int mg = m0 + chv*32 + rr;
      int ng = n0 + co;
      long oidx = (long)z*65536 + (long)mg*256 + ng;
      float4 o0, o1;
      o0.x = ldsF[rr*136+co+0]; o0.y = ldsF[rr*136+co+1];
      o0.z = ldsF[rr*136+co+2]; o0.w = ldsF[rr*136+co+3];
      o1.x = ldsF[rr*136+co+4]; o1.y = ldsF[rr*136+co+5];
      o1.z = ldsF[rr*136+co+6]; o1.w = ldsF[rr*136+co+7];
      *(float4*)(Gp + oidx)     = o0;
      *(float4*)(Gp + oidx + 4) = o1;
    }
  }
}

// ---------------- final fused kernel ----------------
// out[bl][s][c] = sum_d v2scr[d][s]*attn2g[c][d] + sum_e X[s][e]*W1[c][e] (3-pass) + b1eff[c]

__global__ __launch_bounds__(256,2) void k_final(
  const unsigned short* __restrict__ v2T,
  const unsigned short* __restrict__ attn2g,
  const unsigned short* __restrict__ Xhi, const unsigned short* __restrict__ Xlo,
  const unsigned short* __restrict__ W1hi, const unsigned short* __restrict__ W1lo,
  const float* __restrict__ b1eff,
  float* __restrict__ out)
{
  __shared__ char lds[32768];
  char* ldsA = lds; char* ldsB = lds + 16384;
  const int tid = threadIdx.x;
  const int l = tid & 63, wid = tid >> 6;
  const int wm = wid >> 1, wn = wid & 1;
  const int lm = l & 15, lk = l >> 4;
  const int fm = wm*64, fn = wn*64;
  const int bl = blockIdx.z;
  const int m0 = blockIdx.x*128;   // s
  const int n0 = blockIdx.y*128;   // c

  f32x4 acc[4][4];
  #pragma unroll
  for (int i=0;i<4;++i)
    #pragma unroll
    for (int j=0;j<4;++j) acc[i][j] = (f32x4){0.f,0.f,0.f,0.f};

  for (int kt=0; kt<16; ++kt) {
    const int ph = kt >> 2;
    const int kq = (kt & 3) << 6;
    if (ph == 0) {
      // A: gather v2scr tile [128 s][64 d]
      #pragma unroll
      for (int it=0; it<4; ++it) {
        int cid = it*256 + tid;
        int d = cid & 63, sc = cid >> 6;
        int dg = kq + d;
        long row = (long)(((bl >> 3)*8 + (dg & 7))*256 + ((bl & 7) << 5) + (dg >> 3));
        union { int4 v; unsigned short u[8]; } ldv;
        ldv.v = *(const int4*)(v2T + row*4096 + m0 + sc*8);
        #pragma unroll
        for (int e=0;e<8;++e) {
          int sl = sc*8 + e;
          int bo = sl*128 + ((d*2) ^ ((sl & 7) << 4));
          *(unsigned short*)(ldsA + bo) = ldv.u[e];
        }
      }
      #pragma unroll
      for (int it=0; it<4; ++it) {
        int idx = it*256 + tid;
        int r = idx >> 3;
        int kb = ((idx & 7) << 4) ^ ((r & 7) << 4);
        long gb = (long)bl*65536 + (long)(n0 + r)*256 + kq + (kb >> 1);
        gload16(attn2g + gb, ldsB + idx*16);
      }
    } else {
      const unsigned short* As = (ph==3) ? Xlo : Xhi;
      const unsigned short* Bs = (ph==2) ? W1lo : W1hi;
      #pragma unroll
      for (int it=0; it<4; ++it) {
        int idx = it*256 + tid;
        int r = idx >> 3;
        int kb = ((idx & 7) << 4) ^ ((r & 7) << 4);
        long ga = (long)bl*1048576 + (long)(m0 + r)*256 + kq + (kb >> 1);
        gload16(As + ga, ldsA + idx*16);
        long gb = (long)bl*65536 + (long)(n0 + r)*256 + kq + (kb >> 1);
        gload16(Bs + gb, ldsB + idx*16);
      }
    }
    __syncthreads();
    #pragma unroll
    for (int kk=0; kk<2; ++kk) {
      bf16x8 a_[4];
      #pragma unroll
      for (int i=0;i<4;++i) {
        int r = fm + i*16 + lm;
        int kb = ((kk<<6) + (lk<<4)) ^ ((r & 7) << 4);
        a_[i] = *(const bf16x8*)(ldsA + r*128 + kb);
      }
      #pragma unroll
      for (int j=0;j<4;++j) {
        int r = fn + j*16 + lm;
        int kb = ((kk<<6) + (lk<<4)) ^ ((r & 7) << 4);
        bf16x8 b_ = *(const bf16x8*)(ldsB + r*128 + kb);
        #pragma unroll
        for (int i=0;i<4;++i)
          acc[i][j] = __builtin_amdgcn_mfma_f32_16x16x32_bf16(a_[i], b_, acc[i][j], 0, 0, 0);
      }
    }
    __syncthreads();
  }

  float* ldsF = (float*)lds;
  #pragma unroll
  for (int chv=0; chv<4; ++chv) {
    __syncthreads();
    if (wm == (chv >> 1)) {
      #pragma unroll
      for (int i2=0;i2<2;++i2) {
        int i = (chv & 1)*2 + i2;
        #pragma unroll
        for (int j=0;j<4;++j) {
          int n = fn + j*16 + lm;
          int m2 = i2*16 + lk*4;
          #pragma unroll
          for (int r2=0;r2<4;++r2) ldsF[(m2+r2)*136 + n] = acc[i][j][r2];
        }
      }
    }
    __syncthreads();
    #pragma unroll
    for (int g2=0; g2<2; ++g2) {
      int t2 = g2*256 + tid;
      int rr = t2 >> 4;
      int co = (t2 & 15) * 8;
      int mg = m0 + chv*32 + rr;     // s
      int ng = n0 + co;              // c
      long oidx = (long)bl*1048576 + (long)mg*256 + ng;
      float4 o0, o1;
      o0.x = ldsF[rr*136+co+0] + b1eff[bl*256+ng+0];
      o0.y = ldsF[rr*136+co+1] + b1eff[bl*256+ng+1];
      o0.z = ldsF[rr*136+co+2] + b1eff[bl*256+ng+2];
      o0.w = ldsF[rr*136+co+3] + b1eff[bl*256+ng+3];
      o1.x = ldsF[rr*136+co+4] + b1eff[bl*256+ng+4];
      o1.y = ldsF[rr*136+co+5] + b1eff[bl*256+ng+5];
      o1.z = ldsF[rr*136+co+6] + b1eff[bl*256+ng+6];
      o1.w = ldsF[rr*136+co+7] + b1eff[bl*256+ng+7];
      *(float4*)(out + oidx)     = o0;
      *(float4*)(out + oidx + 4) = o1;
    }
  }
}

// ---------------- launch ----------------

extern "C" void kernel_launch(void* const* d_in, const int* in_sizes, int n_in,
                              void* d_out, int out_size, void* d_ws, size_t ws_size,
                              hipStream_t stream)
{
  const float* x    = (const float*)d_in[0];
  const float* sq_w = (const float*)d_in[3];
  const float* sq_b = (const float*)d_in[4];
  const float* sk_w = (const float*)d_in[5];
  const float* sk_b = (const float*)d_in[6];
  const float* sv_w = (const float*)d_in[7];
  const float* sv_b = (const float*)d_in[8];
  const float* tq_w = (const float*)d_in[9];
  const float* tq_b = (const float*)d_in[10];
  const float* tk_w = (const float*)d_in[11];
  const float* tk_b = (const float*)d_in[12];
  const float* tv_w = (const float*)d_in[13];
  const float* tv_b = (const float*)d_in[14];
  const float* s_g  = (const float*)d_in[15];
  const float* t_g  = (const float*)d_in[16];

  char* p = (char*)d_ws;
  size_t off = 0;
  auto take = [&](size_t n){ char* r = p + off; off = (off + n + 255) & ~(size_t)255; return r; };

  unsigned short* Whi    = (unsigned short*)take((size_t)6*65536*2);
  unsigned short* Wlo    = (unsigned short*)take((size_t)6*65536*2);
  unsigned short* WvThi  = (unsigned short*)take((size_t)65536*2);
  unsigned short* WvTlo  = (unsigned short*)take((size_t)65536*2);
  unsigned short* Xhi    = (unsigned short*)take((size_t)16*S4*CH*2);
  unsigned short* Xlo    = (unsigned short*)take((size_t)16*S4*CH*2);
  unsigned short* v2T    = (unsigned short*)take((size_t)16*S4*CH*2);
  float*          Gp     = (float*)take((size_t)64*65536*4);
  unsigned short* G1hi   = (unsigned short*)take((size_t)16*65536*2);
  unsigned short* G1lo   = (unsigned short*)take((size_t)16*65536*2);
  unsigned short* GShi   = (unsigned short*)take((size_t)16*65536*2);
  unsigned short* GSlo   = (unsigned short*)take((size_t)16*65536*2);
  unsigned short* Pthi   = (unsigned short*)take((size_t)16*65536*2);
  unsigned short* Ptlo   = (unsigned short*)take((size_t)16*65536*2);
  unsigned short* G2hi   = (unsigned short*)take((size_t)16*65536*2);
  unsigned short* G2lo   = (unsigned short*)take((size_t)16*65536*2);
  unsigned short* W1hi   = (unsigned short*)take((size_t)16*65536*2);
  unsigned short* W1lo   = (unsigned short*)take((size_t)16*65536*2);
  unsigned short* a1hi   = (unsigned short*)take((size_t)16*65536*2);
  unsigned short* a1lo   = (unsigned short*)take((size_t)16*65536*2);
  unsigned short* a2g    = (unsigned short*)take((size_t)16*65536*2);
  float*          M1     = (float*)take((size_t)16*65536*4);
  float*          logits = (float*)take((size_t)16*65536*4);
  float*          ups    = (float*)take((size_t)16*32*256*4);
  float*          u      = (float*)take((size_t)16*256*4);
  float*          wqu    = (float*)take((size_t)16*256*4);
  float*          wku    = (float*)take((size_t)16*256*4);
  float*          wtku   = (float*)take((size_t)16*256*4);
  float*          c1     = (float*)take((size_t)16*256*4);
  float*          m1u    = (float*)take((size_t)16*256*4);
  float*          b1eff  = (float*)take((size_t)16*256*4);
  float*          wtqh   = (float*)take((size_t)16*256*4);

  const long XBL = (long)S4*CH;     // 1048576
  const long GBL = 65536;

  k_wprep<<<dim3(1792), 256, 0, stream>>>(sq_w, sk_w, sv_w, tq_w, tk_w, tv_w,
                                          Whi, Wlo, WvThi, WvTlo);
  k_xprep<<<dim3(65536), 256, 0, stream>>>(x, Xhi, Xlo);

  // Gram G1 = X^T X (partials, combine)
  k_gram<false><<<dim3(2,2,64), 256, 0, stream>>>(Xhi, Xlo, Gp);
  k_gcomb<<<dim3(256,16), 256, 0, stream>>>(Gp, G1hi, G1lo);
  // Gram GS = sum_s x_s x_swap(s)^T  (symmetric)
  k_gram<true><<<dim3(2,2,64), 256, 0, stream>>>(Xhi, Xlo, Gp);
  k_gcomb<<<dim3(256,16), 256, 0, stream>>>(Gp, GShi, GSlo);

  // u, rank-1 vectors
  k_colsum<<<dim3(16,32), 256, 0, stream>>>(x, ups);
  k_vecfin<<<dim3(16), 256, 0, stream>>>(ups, u);
  k_vecs1<<<dim3(16,3), 256, 0, stream>>>(sq_w, sq_b, sk_w, tk_w, u, wqu, wku, wtku);

  // Pt1[d][e] = sum_f Wk[d][f] G1[e][f]
  k_gemm<true,0><<<dim3(2,2,16), 256, 0, stream>>>(
     Whi+1*65536, Wlo+1*65536, 0, 256,  G1hi, G1lo, GBL, 256,
     nullptr, nullptr,0,nullptr,0, nullptr,0,nullptr,0,
     Pthi, Ptlo, nullptr, GBL, 256);
  // L1[c][d] = sum_e Wq[c][e] Pt1[d][e] + wqu'[c]*bk[d] + bq[c]*wku[d]
  k_gemm<true,5><<<dim3(2,2,16), 256, 0, stream>>>(
     Whi+0*65536, Wlo+0*65536, 0, 256,  Pthi, Ptlo, GBL, 256,
     nullptr, wqu,256, sk_b,0,  sq_b,0, wku,256,
     nullptr, nullptr, logits, GBL, 256);
  k_softmax<0><<<dim3(1024), 256, 0, stream>>>(logits, nullptr, a1hi, a1lo);

  // M1[c][e] = sum_d attn1[c][d] Wv[d][e]
  k_gemm<true,2><<<dim3(2,2,16), 256, 0, stream>>>(
     a1hi, a1lo, GBL, 256,  WvThi, WvTlo, 0, 256,
     nullptr, nullptr,0,nullptr,0, nullptr,0,nullptr,0,
     nullptr, nullptr, M1, GBL, 256);
  k_w1eff<<<dim3(256,16), 256, 0, stream>>>(M1, s_g, W1hi, W1lo);
  k_vecs2a<<<dim3(16,2), 256, 0, stream>>>(a1hi, a1lo, sv_b, M1, u, c1, m1u);
  k_vecs2b<<<dim3(16), 256, 0, stream>>>(u, m1u, c1, s_g, tq_w, tq_b, b1eff, wtqh);

  // G2[c'][f] = sum_e W1[c'][e] GS[e][f] + b1eff[c']*u[f]
  k_gemm<true,0><<<dim3(2,2,16), 256, 0, stream>>>(
     W1hi, W1lo, GBL, 256,  GShi, GSlo, GBL, 256,
     nullptr, b1eff,256, u,256,  nullptr,0,nullptr,0,
     G2hi, G2lo, nullptr, GBL, 256);
  // Pt2[d][c'] = sum_f Wtk[d][f] G2[c'][f]
  k_gemm<true,0><<<dim3(2,2,16), 256, 0, stream>>>(
     Whi+4*65536, Wlo+4*65536, 0, 256,  G2hi, G2lo, GBL, 256,
     nullptr, nullptr,0,nullptr,0, nullptr,0,nullptr,0,
     Pthi, Ptlo, nullptr, GBL, 256);
  // L2[c][d] = sum_e Wtq[c][e] Pt2[d][e] + wtqh'[c]*btk[d] + btq[c]*wtku[d]
  k_gemm<true,5><<<dim3(2,2,16), 256, 0, stream>>>(
     Whi+3*65536, Wlo+3*65536, 0, 256,  Pthi, Ptlo, GBL, 256,
     nullptr, wtqh,256, tk_b,0,  tq_b,0, wtku,256,
     nullptr, nullptr, logits, GBL, 256);
  k_softmax<1><<<dim3(1024), 256, 0, stream>>>(logits, t_g, a2g, nullptr);

  // v2 conv: v2T[bl][dv][s] = sum_e Wtv[dv][e] X[s][e] + btv[dv]
  k_gemm<false,1><<<dim3(2,32,16), 256, 0, stream>>>(
     Whi+5*65536, nullptr, 0, 256,  Xhi, nullptr, XBL, 256,
     tv_b, nullptr,0,nullptr,0, nullptr,0,nullptr,0,
     v2T, nullptr, nullptr, XBL, S4);

  // final fused output
  k_final<<<dim3(32,2,16), 256, 0, stream>>>(v2T, a2g, Xhi, Xlo, W1hi, W1lo, b1eff, (float*)d_out);
}